// Round 3
// baseline (805.823 us; speedup 1.0000x reference)
//
#include <hip/hip_runtime.h>
#include <math.h>

// ---------------------------------------------------------------------------
// RepirDet head forward, MI355X f32 implementation (round 3).
//  k_sig    : out2 = sigmoid(classify_logits)
//  k_topk   : per-batch exact 819th-largest logit (radix select, LDS keys)
//  k_dwln   : FUSED dw7x7 + mask + LN + pw1 + gelu -> y1 (chunk-channel-major)
//  k_grn    : fold GRN scale into pw2 weights (per batch)
//  k_pw2    : y1c @ W2s + bias2 + shortcut -> x_nhwc   (no LDS staging)
//  k_conv3  : 3x3 conv, double-buffered LDS staging (up +bn1 / shortcut +bn2+relu)
//  k_lastup : bilinear2x(E) on the fly + concat(D) + 3x3 conv -> A
//  k_final  : bilinear 2x (256->512) + 5x5 conv + sigmoid -> out1
// ---------------------------------------------------------------------------

__device__ __forceinline__ float erf_fast(float x) {
  float ax = fabsf(x);
  float t = __builtin_amdgcn_rcpf(fmaf(0.3275911f, ax, 1.f));
  float poly = t * fmaf(t, fmaf(t, fmaf(t, fmaf(t, 1.061405429f, -1.453152027f),
                                        1.421413741f), -0.284496736f), 0.254829592f);
  float r = 1.f - poly * __expf(-ax * ax);
  return copysignf(r, x);
}

__global__ void k_sig(const float* __restrict__ lg, float* __restrict__ out) {
  int i = blockIdx.x * 256 + threadIdx.x;
  float4 v = reinterpret_cast<const float4*>(lg)[i];
  float4 r;
  r.x = 1.f / (1.f + __expf(-v.x));
  r.y = 1.f / (1.f + __expf(-v.y));
  r.z = 1.f / (1.f + __expf(-v.z));
  r.w = 1.f / (1.f + __expf(-v.w));
  reinterpret_cast<float4*>(out)[i] = r;
}

__global__ __launch_bounds__(1024) void k_topk(const float* __restrict__ lg,
                                               float* __restrict__ thr) {
  __shared__ unsigned keys[16384];
  __shared__ unsigned hist[256];
  __shared__ unsigned sh_prefix, sh_krem;
  int b = blockIdx.x, t = threadIdx.x;
  if (t < 256) hist[t] = 0u;
  if (t == 0) { sh_prefix = 0u; sh_krem = 819u; }
  __syncthreads();
  for (int i = t; i < 16384; i += 1024) {
    float vF = lg[(b << 16) + ((i >> 7) << 9) + ((i & 127) << 1)];
    unsigned u = __float_as_uint(vF);
    unsigned key = (u & 0x80000000u) ? ~u : (u | 0x80000000u);
    keys[i] = key;
    atomicAdd(&hist[key >> 24], 1u);
  }
  for (int pass = 0; pass < 4; ++pass) {
    __syncthreads();
    if (t == 0) {
      unsigned krem = sh_krem, c = 0;
      int bin = 255;
      for (; bin >= 0; --bin) {
        unsigned c2 = c + hist[bin];
        if (c2 >= krem) break;
        c = c2;
      }
      sh_prefix = (sh_prefix << 8) | (unsigned)bin;
      sh_krem = krem - c;
    }
    __syncthreads();
    if (pass < 3) {
      if (t < 256) hist[t] = 0u;
      __syncthreads();
      int shift = 16 - 8 * pass;
      unsigned pref = sh_prefix;
      for (int i = t; i < 16384; i += 1024) {
        unsigned key = keys[i];
        if ((key >> (shift + 8)) == pref) atomicAdd(&hist[(key >> shift) & 255u], 1u);
      }
    }
  }
  __syncthreads();
  if (t == 0) {
    unsigned key = sh_prefix;
    unsigned u = (key & 0x80000000u) ? (key ^ 0x80000000u) : ~key;
    thr[b] = __uint_as_float(u);
  }
}

#define FMA8(i, xc)                                                           \
  acc[i][0] = fmaf(xc, wA.x, acc[i][0]); acc[i][1] = fmaf(xc, wA.y, acc[i][1]); \
  acc[i][2] = fmaf(xc, wA.z, acc[i][2]); acc[i][3] = fmaf(xc, wA.w, acc[i][3]); \
  acc[i][4] = fmaf(xc, wB.x, acc[i][4]); acc[i][5] = fmaf(xc, wB.y, acc[i][5]); \
  acc[i][6] = fmaf(xc, wB.z, acc[i][6]); acc[i][7] = fmaf(xc, wB.w, acc[i][7]);

// FUSED dw7x7 + mask + LN + pw1 + gelu. grid (8,8,16), 256 thr.
// y1 output layout: [b][chunk=by*8+bx][c 0..31][px 0..255]  (channel-major)
__global__ __launch_bounds__(256) void k_dwln(
    const float* __restrict__ feats4x, const float* __restrict__ lg,
    const float* __restrict__ thr, const float* __restrict__ dw_w,
    const float* __restrict__ dw_b, const float* __restrict__ lng,
    const float* __restrict__ lnb, const float* __restrict__ w1,
    const float* __restrict__ b1, float* __restrict__ y1,
    float* __restrict__ gss) {
  int bx = blockIdx.x, by = blockIdx.y, b = blockIdx.z;
  int t = threadIdx.x;
  __shared__ __align__(16) float hx[2][4][22][24];
  __shared__ __align__(16) float xT[32][256];
  __shared__ __align__(16) float w1T[32][32];
  __shared__ __align__(16) float wdw[32][52];
  __shared__ float sB1[32], sLng[32], sLnb[32];
  for (int i = t; i < 1024; i += 256) w1T[i & 31][i >> 5] = w1[i];
  for (int i = t; i < 1568; i += 256) wdw[i / 49][i % 49] = dw_w[i];
  if (t < 32) { sB1[t] = b1[t]; sLng[t] = lng[t]; sLnb[t] = lnb[t]; }
  int wave = t >> 6, strip = t & 63;
  int py = strip >> 2, px0 = (strip & 3) << 2;

  auto stageH = [&](int g, int buf) {
#pragma unroll
    for (int k = 0; k < 3; ++k) {
      int i = t + (k << 8);
      if (i < 528) {
        int cl = i / 132, rem = i - cl * 132;
        int hy = rem / 6, hq = rem - hy * 6;
        int gy = (by << 4) + hy - 3;
        int qx = (bx << 4) + (hq << 2) - 4;
        float4 v = make_float4(0.f, 0.f, 0.f, 0.f);
        if ((unsigned)gy < 128u && (unsigned)qx < 128u)
          v = *reinterpret_cast<const float4*>(
              feats4x + (((b << 5) + (g << 2) + cl) << 14) + (gy << 7) + qx);
        *reinterpret_cast<float4*>(&hx[buf][cl][hy][hq << 2]) = v;
      }
    }
  };
  auto computeDW = [&](int g, int buf) {
    int c = (g << 2) + wave;
    float wr[49];
#pragma unroll
    for (int q = 0; q < 12; ++q)
      *reinterpret_cast<float4*>(&wr[q << 2]) =
          *reinterpret_cast<const float4*>(&wdw[c][q << 2]);
    wr[48] = wdw[c][48];
    float bb = dw_b[c];
    float a0 = bb, a1 = bb, a2 = bb, a3 = bb;
#pragma unroll
    for (int ky = 0; ky < 7; ++ky) {
      const float* row = &hx[buf][wave][py + ky][px0];
      float4 r0 = *reinterpret_cast<const float4*>(row);
      float4 r1 = *reinterpret_cast<const float4*>(row + 4);
      float4 r2 = *reinterpret_cast<const float4*>(row + 8);
      float rr[12] = {r0.x, r0.y, r0.z, r0.w, r1.x, r1.y, r1.z, r1.w,
                      r2.x, r2.y, r2.z, r2.w};
#pragma unroll
      for (int kx = 0; kx < 7; ++kx) {
        float wv = wr[ky * 7 + kx];
        a0 = fmaf(rr[kx + 1], wv, a0);
        a1 = fmaf(rr[kx + 2], wv, a1);
        a2 = fmaf(rr[kx + 3], wv, a2);
        a3 = fmaf(rr[kx + 4], wv, a3);
      }
    }
    *reinterpret_cast<float4*>(&xT[c][strip << 2]) = make_float4(a0, a1, a2, a3);
  };

  stageH(0, 0);
  __syncthreads();
#pragma unroll
  for (int g = 0; g < 8; ++g) {
    if (g < 7) stageH(g + 1, (g + 1) & 1);
    computeDW(g, g & 1);
    __syncthreads();
  }
  // ---- per-pixel LN (thread t owns pixel column t) ----
  {
    float tv = thr[b];
    int gpy = (by << 4) + (t >> 4), gpx = (bx << 4) + (t & 15);
    bool act = lg[(b << 16) + (gpy << 9) + (gpx << 1)] > tv;
    float v[32];
    float s = 0.f, s2 = 0.f;
#pragma unroll
    for (int c = 0; c < 32; ++c) {
      float q = xT[c][t];
      v[c] = q;
      s += q;
      s2 += q * q;
    }
    float mu = s * 0.03125f;
    float var = fmaxf(s2 * 0.03125f - mu * mu, 0.f);
    float rs = act ? rsqrtf(var + 1e-6f) : 0.f;
    float mb = act ? 1.f : 0.f;
#pragma unroll
    for (int c = 0; c < 32; ++c)
      xT[c][t] = (v[c] - mu) * rs * sLng[c] + sLnb[c] * mb;
  }
  __syncthreads();
  // ---- pw1 GEMM + gelu + y1c store + gss atomics ----
  int p = t & 63, j0 = wave << 3;
  float acc[4][8];
#pragma unroll
  for (int j = 0; j < 8; ++j) {
    float bj = sB1[j0 + j];
    acc[0][j] = bj; acc[1][j] = bj; acc[2][j] = bj; acc[3][j] = bj;
  }
#pragma unroll
  for (int c = 0; c < 32; ++c) {
    float4 xv = *reinterpret_cast<const float4*>(&xT[c][p << 2]);
    float4 wA = *reinterpret_cast<const float4*>(&w1T[c][j0]);
    float4 wB = *reinterpret_cast<const float4*>(&w1T[c][j0 + 4]);
    FMA8(0, xv.x) FMA8(1, xv.y) FMA8(2, xv.z) FMA8(3, xv.w)
  }
  float part[8] = {0, 0, 0, 0, 0, 0, 0, 0};
#pragma unroll
  for (int i = 0; i < 4; ++i) {
#pragma unroll
    for (int j = 0; j < 8; ++j) {
      float u = acc[i][j];
      float gl = 0.5f * u * (1.f + erf_fast(u * 0.70710678f));
      acc[i][j] = gl;
      part[j] += gl * gl;
    }
  }
  int chunk = (by << 3) + bx;
#pragma unroll
  for (int j = 0; j < 8; ++j) {
    float* yp = y1 + ((((b << 6) + chunk) << 5) + j0 + j) * 256 + (p << 2);
    *reinterpret_cast<float4*>(yp) =
        make_float4(acc[0][j], acc[1][j], acc[2][j], acc[3][j]);
  }
#pragma unroll
  for (int j = 0; j < 8; ++j) {
    float pv = part[j];
#pragma unroll
    for (int off = 1; off < 64; off <<= 1) pv += __shfl_xor(pv, off, 64);
    if (p == 0) atomicAdd(&gss[(b << 5) + j0 + j], pv);
  }
}

__global__ void k_grn(const float* __restrict__ gss, const float* __restrict__ grng,
                      const float* __restrict__ grnb, const float* __restrict__ w2,
                      const float* __restrict__ b2, float* __restrict__ w2sT,
                      float* __restrict__ bias2) {
  int b = blockIdx.x, t = threadIdx.x;
  __shared__ float gxs[32], sc[32];
  if (t < 32) gxs[t] = sqrtf(gss[(b << 5) + t]);
  __syncthreads();
  if (t < 32) {
    float m = 0.f;
#pragma unroll
    for (int c = 0; c < 32; ++c) m += gxs[c];
    m = m * 0.03125f + 1e-6f;
    sc[t] = grng[t] * (gxs[t] / m) + 1.f;
  }
  __syncthreads();
  for (int i = t; i < 1024; i += 256) {
    int c = i >> 5, j = i & 31;
    w2sT[(b << 10) + i] = w2[j * 32 + c] * sc[c];
  }
  if (t < 32) {
    float s = 0.f;
#pragma unroll
    for (int c = 0; c < 32; ++c) s += grnb[c] * w2[t * 32 + c];
    bias2[(b << 5) + t] = s + b2[t];
  }
}

// y1c @ W2s + bias2 + shortcut(feats4x NCHW) -> x_nhwc.  grid 1024, 256 thr.
__global__ __launch_bounds__(256) void k_pw2(
    const float* __restrict__ y1c, const float* __restrict__ w2sT,
    const float* __restrict__ bias2, const float* __restrict__ f4,
    float* __restrict__ xo) {
  int b = blockIdx.x >> 6, chunk = blockIdx.x & 63, t = threadIdx.x;
  __shared__ __align__(16) float wT[32][32];
  __shared__ float sb2[32];
  for (int i = t; i < 1024; i += 256) wT[i >> 5][i & 31] = w2sT[(b << 10) + i];
  if (t < 32) sb2[t] = bias2[(b << 5) + t];
  int p = t & 63, j0 = (t >> 6) << 3;
  const float* xp = y1c + (((b << 6) + chunk) << 13) + (p << 2);
  __syncthreads();
  float acc[4][8];
#pragma unroll
  for (int j = 0; j < 8; ++j) {
    float bj = sb2[j0 + j];
    acc[0][j] = bj; acc[1][j] = bj; acc[2][j] = bj; acc[3][j] = bj;
  }
#pragma unroll
  for (int c = 0; c < 32; ++c) {
    float4 xv = *reinterpret_cast<const float4*>(xp + (c << 8));
    float4 wA = *reinterpret_cast<const float4*>(&wT[c][j0]);
    float4 wB = *reinterpret_cast<const float4*>(&wT[c][j0 + 4]);
    FMA8(0, xv.x) FMA8(1, xv.y) FMA8(2, xv.z) FMA8(3, xv.w)
  }
  int ty = chunk >> 3, tx = chunk & 7;
  int y = (ty << 4) + (p >> 2), xb = (tx << 4) + ((p << 2) & 15);
#pragma unroll
  for (int j = 0; j < 8; ++j) {
    float4 sc4 = *reinterpret_cast<const float4*>(
        f4 + (((b << 5) + j0 + j) << 14) + (y << 7) + xb);
    acc[0][j] += sc4.x; acc[1][j] += sc4.y; acc[2][j] += sc4.z; acc[3][j] += sc4.w;
  }
#pragma unroll
  for (int i = 0; i < 4; ++i) {
    float* op = xo + (((b << 14) + (y << 7) + xb + i) << 5) + j0;
    *reinterpret_cast<float4*>(op) = make_float4(acc[i][0], acc[i][1], acc[i][2], acc[i][3]);
    *reinterpret_cast<float4*>(op + 4) = make_float4(acc[i][4], acc[i][5], acc[i][6], acc[i][7]);
  }
}

// 3x3 conv, pad 1, 32x32 tile, 4 px/thread, double-buffered staging.
// MODE 0: NHWC in (IC=32), +bias+bn        (up branch)
// MODE 1: NCHW in (IC=16), +bias+bn+relu   (shortcut branch)
template <int IC, int OC, int HH, int WW, int MODE>
__global__ __launch_bounds__(256) void k_conv3(
    const float* __restrict__ xin,
    const float* __restrict__ wgt, const float* __restrict__ bias,
    const float* __restrict__ bng, const float* __restrict__ bnb,
    const float* __restrict__ bnm, const float* __restrict__ bnv,
    float* __restrict__ out) {
  constexpr int NG = IC / 4;
  int bx = blockIdx.x << 5, by = blockIdx.y << 5, b = blockIdx.z;
  int t = threadIdx.x;
  int py = t >> 3, px0 = (t & 7) << 2;
  __shared__ __align__(16) float4 xt[2][34 * 35];
  __shared__ __align__(16) float4 wt[NG * 9 * OC];
  for (int idx = t; idx < NG * 9 * OC; idx += 256) {
    int g = idx / (9 * OC);
    int rem = idx - g * 9 * OC;
    int tap = rem / OC, o = rem - tap * OC;
    int ky = tap / 3, kx = tap - ky * 3;
    float4 wv;
    wv.x = wgt[((o * IC + g * 4 + 0) * 3 + ky) * 3 + kx];
    wv.y = wgt[((o * IC + g * 4 + 1) * 3 + ky) * 3 + kx];
    wv.z = wgt[((o * IC + g * 4 + 2) * 3 + ky) * 3 + kx];
    wv.w = wgt[((o * IC + g * 4 + 3) * 3 + ky) * 3 + kx];
    wt[idx] = wv;
  }
  float acc[4][OC];
#pragma unroll
  for (int i = 0; i < 4; ++i)
#pragma unroll
    for (int o = 0; o < OC; ++o) acc[i][o] = 0.f;

  auto stage = [&](int g, int buf) {
#pragma unroll
    for (int k = 0; k < 5; ++k) {
      int i = t + (k << 8);
      if (i < 1156) {
        int r = i / 34, c = i - r * 34;
        int gy = by - 1 + r, gx = bx - 1 + c;
        float4 v = make_float4(0.f, 0.f, 0.f, 0.f);
        if ((unsigned)gy < (unsigned)HH && (unsigned)gx < (unsigned)WW) {
          if (MODE == 1) {
            const float* p0 = xin + (((b * IC + (g << 2)) * HH + gy) * WW) + gx;
            v.x = p0[0]; v.y = p0[HH * WW]; v.z = p0[2 * HH * WW]; v.w = p0[3 * HH * WW];
          } else {
            v = *reinterpret_cast<const float4*>(
                xin + (((b * HH) + gy) * WW + gx) * IC + (g << 2));
          }
        }
        xt[buf][r * 35 + c] = v;
      }
    }
  };
  auto compute = [&](int g, int buf) {
#pragma unroll
    for (int ky = 0; ky < 3; ++ky) {
      float4 xr[6];
#pragma unroll
      for (int q = 0; q < 6; ++q) xr[q] = xt[buf][(py + ky) * 35 + px0 + q];
#pragma unroll
      for (int kx = 0; kx < 3; ++kx)
#pragma unroll
        for (int o = 0; o < OC; ++o) {
          float4 wv = wt[(g * 9 + ky * 3 + kx) * OC + o];
#pragma unroll
          for (int i = 0; i < 4; ++i) {
            float4 xv = xr[kx + i];
            acc[i][o] = fmaf(xv.w, wv.w, fmaf(xv.z, wv.z, fmaf(xv.y, wv.y, fmaf(xv.x, wv.x, acc[i][o]))));
          }
        }
    }
  };

  stage(0, 0);
  __syncthreads();
#pragma unroll
  for (int g = 0; g < NG; ++g) {
    if (g + 1 < NG) stage(g + 1, (g + 1) & 1);
    compute(g, g & 1);
    __syncthreads();
  }
  float scl[OC], sbs[OC];
#pragma unroll
  for (int o = 0; o < OC; ++o) {
    float rs = rsqrtf(bnv[o] + 1e-5f) * bng[o];
    scl[o] = rs;
    sbs[o] = (bias[o] - bnm[o]) * rs + bnb[o];
  }
  int gy = by + py;
#pragma unroll
  for (int i = 0; i < 4; ++i) {
    int gx = bx + px0 + i;
    float ov[OC];
#pragma unroll
    for (int o = 0; o < OC; ++o) {
      float u = acc[i][o] * scl[o] + sbs[o];
      if (MODE == 1) u = fmaxf(u, 0.f);
      ov[o] = u;
    }
    float* op = out + ((b * HH * WW) + gy * WW + gx) * OC;
    *reinterpret_cast<float4*>(op) = make_float4(ov[0], ov[1], ov[2], ov[3]);
    if (OC == 8)
      *reinterpret_cast<float4*>(op + 4) = make_float4(ov[4], ov[5], ov[6], ov[7]);
  }
}

// last 3x3 conv with on-the-fly bilinear-2x of E (up branch) + D (shortcut).
// out tile 32x32 at 256^2, grid (8,8,16).
__global__ __launch_bounds__(256) void k_lastup(
    const float* __restrict__ E, const float* __restrict__ D,
    const float* __restrict__ wgt, const float* __restrict__ bias,
    float* __restrict__ out) {
  int bx = blockIdx.x << 5, by = blockIdx.y << 5, b = blockIdx.z;
  int t = threadIdx.x;
  int py = t >> 3, px0 = (t & 7) << 2;
  __shared__ __align__(16) float4 et[19][22][2];
  __shared__ __align__(16) float4 xt[34 * 35];
  __shared__ __align__(16) float4 wt[144];
  for (int idx = t; idx < 144; idx += 256) {
    int g = idx / 36, rem = idx - g * 36;
    int tap = rem >> 2, o = rem & 3;
    int ky = tap / 3, kx = tap - ky * 3;
    float4 wv;
    wv.x = wgt[((o * 16 + g * 4 + 0) * 3 + ky) * 3 + kx];
    wv.y = wgt[((o * 16 + g * 4 + 1) * 3 + ky) * 3 + kx];
    wv.z = wgt[((o * 16 + g * 4 + 2) * 3 + ky) * 3 + kx];
    wv.w = wgt[((o * 16 + g * 4 + 3) * 3 + ky) * 3 + kx];
    wt[idx] = wv;
  }
  // prefetch D halo (ic groups 2,3 of the concat) into registers
  float4 dreg[2][5];
#pragma unroll
  for (int h = 0; h < 2; ++h)
#pragma unroll
    for (int k = 0; k < 5; ++k) {
      int i = t + (k << 8);
      float4 v = make_float4(0.f, 0.f, 0.f, 0.f);
      if (i < 1156) {
        int r = i / 34, c = i - r * 34;
        int gy = by - 1 + r, gx = bx - 1 + c;
        if ((unsigned)gy < 256u && (unsigned)gx < 256u)
          v = *reinterpret_cast<const float4*>(
              D + (((b << 16) + (gy << 8) + gx) << 3) + (h << 2));
      }
      dreg[h][k] = v;
    }
  // stage E tile (rows ey0..ey0+18, cols ex0..ex0+21, clamped)
  int ey0 = (by >> 1) - 1, ex0 = (bx >> 1) - 3;
#pragma unroll
  for (int k = 0; k < 4; ++k) {
    int i = t + (k << 8);
    if (i < 836) {
      int h = i & 1, q = i >> 1;
      int r = q / 22, c = q - r * 22;
      int er = min(max(ey0 + r, 0), 127), ec = min(max(ex0 + c, 0), 127);
      et[r][c][h] = *reinterpret_cast<const float4*>(
          E + (((b << 14) + (er << 7) + ec) << 3) + (h << 2));
    }
  }
  float acc[4][4];
#pragma unroll
  for (int i = 0; i < 4; ++i)
#pragma unroll
    for (int o = 0; o < 4; ++o) acc[i][o] = 0.f;

  auto compute = [&](int g) {
#pragma unroll
    for (int ky = 0; ky < 3; ++ky) {
      float4 xr[6];
#pragma unroll
      for (int q = 0; q < 6; ++q) xr[q] = xt[(py + ky) * 35 + px0 + q];
#pragma unroll
      for (int kx = 0; kx < 3; ++kx)
#pragma unroll
        for (int o = 0; o < 4; ++o) {
          float4 wv = wt[(g * 9 + ky * 3 + kx) * 4 + o];
#pragma unroll
          for (int i = 0; i < 4; ++i) {
            float4 xv = xr[kx + i];
            acc[i][o] = fmaf(xv.w, wv.w, fmaf(xv.z, wv.z, fmaf(xv.y, wv.y, fmaf(xv.x, wv.x, acc[i][o]))));
          }
        }
    }
  };

  // groups 2,3: D (register-prefetched)
#pragma unroll
  for (int h = 0; h < 2; ++h) {
    __syncthreads();
#pragma unroll
    for (int k = 0; k < 5; ++k) {
      int i = t + (k << 8);
      if (i < 1156) xt[(i / 34) * 35 + (i - (i / 34) * 34)] = dreg[h][k];
    }
    __syncthreads();
    compute(2 + h);
  }
  // groups 0,1: bilinear-upsampled E
#pragma unroll
  for (int h = 0; h < 2; ++h) {
    __syncthreads();
#pragma unroll
    for (int k = 0; k < 5; ++k) {
      int i = t + (k << 8);
      if (i < 1156) {
        int r = i / 34, c = i - r * 34;
        int gy = by - 1 + r, gx = bx - 1 + c;
        float4 uv = make_float4(0.f, 0.f, 0.f, 0.f);
        if ((unsigned)gy < 256u && (unsigned)gx < 256u) {
          int r0 = (gy - 1) >> 1, c0 = (gx - 1) >> 1;
          float fy = (gy & 1) ? 0.25f : 0.75f;
          float fx = (gx & 1) ? 0.25f : 0.75f;
          int ra = max(r0, 0) - ey0, rb = min(r0 + 1, 127) - ey0;
          int ca = max(c0, 0) - ex0, cb = min(c0 + 1, 127) - ex0;
          float w00 = (1.f - fy) * (1.f - fx), w01 = (1.f - fy) * fx;
          float w10 = fy * (1.f - fx), w11 = fy * fx;
          float4 a = et[ra][ca][h], bq = et[ra][cb][h];
          float4 cq = et[rb][ca][h], dq = et[rb][cb][h];
          uv.x = w00 * a.x + w01 * bq.x + w10 * cq.x + w11 * dq.x;
          uv.y = w00 * a.y + w01 * bq.y + w10 * cq.y + w11 * dq.y;
          uv.z = w00 * a.z + w01 * bq.z + w10 * cq.z + w11 * dq.z;
          uv.w = w00 * a.w + w01 * bq.w + w10 * cq.w + w11 * dq.w;
        }
        xt[r * 35 + c] = uv;
      }
    }
    __syncthreads();
    compute(h);
  }
  float b0 = bias[0], b1v = bias[1], b2v = bias[2], b3v = bias[3];
  int gy = by + py;
#pragma unroll
  for (int i = 0; i < 4; ++i) {
    int gx = bx + px0 + i;
    float* op = out + (((b << 16) + (gy << 8) + gx) << 2);
    *reinterpret_cast<float4*>(op) = make_float4(acc[i][0] + b0, acc[i][1] + b1v,
                                                 acc[i][2] + b2v, acc[i][3] + b3v);
  }
}

// bilinear 2x (256->512, zero outside) + 5x5 conv pad 2 + sigmoid -> out1
__global__ __launch_bounds__(256) void k_final(
    const float* __restrict__ v4, const float* __restrict__ w5,
    const float* __restrict__ b5, float* __restrict__ out) {
  int bx = blockIdx.x << 5, by = blockIdx.y << 5, b = blockIdx.z;
  int t = threadIdx.x;
  __shared__ __align__(16) float4 vt[20 * 20];
  __shared__ __align__(16) float4 ut[36 * 38];
  int vy0 = (by >> 1) - 2, vx0 = (bx >> 1) - 2;
  for (int i = t; i < 400; i += 256) {
    int r = i / 20, c = i - r * 20;
    int gy = vy0 + r, gx = vx0 + c;
    float4 v = make_float4(0.f, 0.f, 0.f, 0.f);
    if (gy >= 0 && gy < 256 && gx >= 0 && gx < 256)
      v = *reinterpret_cast<const float4*>(v4 + ((b << 16) + gy * 256 + gx) * 4);
    vt[i] = v;
  }
  __syncthreads();
  for (int i = t; i < 36 * 36; i += 256) {
    int r = i / 36, c = i - r * 36;
    int yy = by - 2 + r, xx = bx - 2 + c;
    float4 uv = make_float4(0.f, 0.f, 0.f, 0.f);
    if (yy >= 0 && yy < 512 && xx >= 0 && xx < 512) {
      int r0 = (yy - 1) >> 1, c0 = (xx - 1) >> 1;
      float fy = (yy & 1) ? 0.25f : 0.75f;
      float fx = (xx & 1) ? 0.25f : 0.75f;
      int ra = max(r0, 0) - vy0, rb = min(r0 + 1, 255) - vy0;
      int ca = max(c0, 0) - vx0, cb = min(c0 + 1, 255) - vx0;
      float4 a = vt[ra * 20 + ca], bq = vt[ra * 20 + cb];
      float4 cq = vt[rb * 20 + ca], dq = vt[rb * 20 + cb];
      float w00 = (1.f - fy) * (1.f - fx), w01 = (1.f - fy) * fx;
      float w10 = fy * (1.f - fx), w11 = fy * fx;
      uv.x = w00 * a.x + w01 * bq.x + w10 * cq.x + w11 * dq.x;
      uv.y = w00 * a.y + w01 * bq.y + w10 * cq.y + w11 * dq.y;
      uv.z = w00 * a.z + w01 * bq.z + w10 * cq.z + w11 * dq.z;
      uv.w = w00 * a.w + w01 * bq.w + w10 * cq.w + w11 * dq.w;
    }
    ut[r * 38 + c] = uv;
  }
  __syncthreads();
  float4 wr[25];
#pragma unroll
  for (int tap = 0; tap < 25; ++tap) {
    wr[tap].x = w5[tap];
    wr[tap].y = w5[25 + tap];
    wr[tap].z = w5[50 + tap];
    wr[tap].w = w5[75 + tap];
  }
  float bb = b5[0];
  int py = (t >> 4) << 1, px = (t & 15) << 1;
  float acc00 = bb, acc01 = bb, acc10 = bb, acc11 = bb;
#pragma unroll
  for (int ri = 0; ri < 6; ++ri) {
    float4 xr[6];
#pragma unroll
    for (int q = 0; q < 6; ++q) xr[q] = ut[(py + ri) * 38 + px + q];
#pragma unroll
    for (int i = 0; i < 2; ++i) {
      int ky = ri - i;
      if (ky >= 0 && ky < 5) {
#pragma unroll
        for (int kx = 0; kx < 5; ++kx) {
          float4 w = wr[ky * 5 + kx];
          float4 xa = xr[kx], xb = xr[kx + 1];
          if (i == 0) {
            acc00 = fmaf(xa.w, w.w, fmaf(xa.z, w.z, fmaf(xa.y, w.y, fmaf(xa.x, w.x, acc00))));
            acc01 = fmaf(xb.w, w.w, fmaf(xb.z, w.z, fmaf(xb.y, w.y, fmaf(xb.x, w.x, acc01))));
          } else {
            acc10 = fmaf(xa.w, w.w, fmaf(xa.z, w.z, fmaf(xa.y, w.y, fmaf(xa.x, w.x, acc10))));
            acc11 = fmaf(xb.w, w.w, fmaf(xb.z, w.z, fmaf(xb.y, w.y, fmaf(xb.x, w.x, acc11))));
          }
        }
      }
    }
  }
  int oy = by + py, ox = bx + px;
  float* op = out + (b << 18) + oy * 512 + ox;
  *reinterpret_cast<float2*>(op) =
      make_float2(1.f / (1.f + __expf(-acc00)), 1.f / (1.f + __expf(-acc01)));
  *reinterpret_cast<float2*>(op + 512) =
      make_float2(1.f / (1.f + __expf(-acc10)), 1.f / (1.f + __expf(-acc11)));
}

extern "C" void kernel_launch(void* const* d_in, const int* in_sizes, int n_in,
                              void* d_out, int out_size, void* d_ws, size_t ws_size,
                              hipStream_t stream) {
  (void)in_sizes; (void)n_in; (void)out_size; (void)ws_size;
  const float* feats4x = (const float*)d_in[0];
  const float* feats2x = (const float*)d_in[1];
  const float* clg     = (const float*)d_in[2];
  const float* dw_w    = (const float*)d_in[3];
  const float* dw_b    = (const float*)d_in[4];
  const float* ln_g    = (const float*)d_in[5];
  const float* ln_b    = (const float*)d_in[6];
  const float* pw1_w   = (const float*)d_in[7];
  const float* pw1_b   = (const float*)d_in[8];
  const float* grn_g   = (const float*)d_in[9];
  const float* grn_b   = (const float*)d_in[10];
  const float* pw2_w   = (const float*)d_in[11];
  const float* pw2_b   = (const float*)d_in[12];
  const float* up_w    = (const float*)d_in[13];
  const float* up_b    = (const float*)d_in[14];
  const float* bn1_g   = (const float*)d_in[15];
  const float* bn1_b   = (const float*)d_in[16];
  const float* bn1_m   = (const float*)d_in[17];
  const float* bn1_v   = (const float*)d_in[18];
  const float* sh_w    = (const float*)d_in[19];
  const float* sh_b    = (const float*)d_in[20];
  const float* bn2_g   = (const float*)d_in[21];
  const float* bn2_b   = (const float*)d_in[22];
  const float* bn2_m   = (const float*)d_in[23];
  const float* bn2_v   = (const float*)d_in[24];
  const float* last_w  = (const float*)d_in[25];
  const float* last_b  = (const float*)d_in[26];
  const float* last2_w = (const float*)d_in[27];
  const float* last2_b = (const float*)d_in[28];
  float* outp = (float*)d_out;
  float* ws = (float*)d_ws;
  float* A    = ws;              // x_nhwc -> lastup out (v4)
  float* Bb   = ws + 8388608;    // y1c
  float* D    = ws + 16777216;   // s8 (shortcut branch, NHWC8 256^2)
  float* E    = ws + 25165824;   // up-conv out (NHWC8 128^2)
  float* thr  = ws + 27262976;
  float* gss  = thr + 16;
  float* w2sT = gss + 512;
  float* bias2 = w2sT + 16384;

  hipMemsetAsync(gss, 0, 512 * sizeof(float), stream);
  k_sig<<<1024, 256, 0, stream>>>(clg, outp + 4194304);
  k_topk<<<16, 1024, 0, stream>>>(clg, thr);
  k_dwln<<<dim3(8, 8, 16), 256, 0, stream>>>(feats4x, clg, thr, dw_w, dw_b,
                                             ln_g, ln_b, pw1_w, pw1_b, Bb, gss);
  k_grn<<<16, 256, 0, stream>>>(gss, grn_g, grn_b, pw2_w, pw2_b, w2sT, bias2);
  k_pw2<<<1024, 256, 0, stream>>>(Bb, w2sT, bias2, feats4x, A);
  k_conv3<32, 8, 128, 128, 0><<<dim3(4, 4, 16), 256, 0, stream>>>(
      A, up_w, up_b, bn1_g, bn1_b, bn1_m, bn1_v, E);
  k_conv3<16, 8, 256, 256, 1><<<dim3(8, 8, 16), 256, 0, stream>>>(
      feats2x, sh_w, sh_b, bn2_g, bn2_b, bn2_m, bn2_v, D);
  k_lastup<<<dim3(8, 8, 16), 256, 0, stream>>>(E, D, last_w, last_b, A);
  k_final<<<dim3(16, 16, 16), 256, 0, stream>>>(A, last2_w, last2_b, outp);
}

// Round 4
// 385.925 us; speedup vs baseline: 2.0880x; 2.0880x over previous
//
#include <hip/hip_runtime.h>
#include <math.h>

// ---------------------------------------------------------------------------
// RepirDet head forward, MI355X f32 implementation (round 4).
// Register-bounded T14 staging: dynamic (#pragma unroll 1) group loops,
// load(g+1) issued under compute(g), single LDS buffer, launch_bounds guard.
// ---------------------------------------------------------------------------

__device__ __forceinline__ float erf_fast(float x) {
  float ax = fabsf(x);
  float t = __builtin_amdgcn_rcpf(fmaf(0.3275911f, ax, 1.f));
  float poly = t * fmaf(t, fmaf(t, fmaf(t, fmaf(t, 1.061405429f, -1.453152027f),
                                        1.421413741f), -0.284496736f), 0.254829592f);
  float r = 1.f - poly * __expf(-ax * ax);
  return copysignf(r, x);
}

__global__ void k_sig(const float* __restrict__ lg, float* __restrict__ out) {
  int i = blockIdx.x * 256 + threadIdx.x;
  float4 v = reinterpret_cast<const float4*>(lg)[i];
  float4 r;
  r.x = 1.f / (1.f + __expf(-v.x));
  r.y = 1.f / (1.f + __expf(-v.y));
  r.z = 1.f / (1.f + __expf(-v.z));
  r.w = 1.f / (1.f + __expf(-v.w));
  reinterpret_cast<float4*>(out)[i] = r;
}

__global__ __launch_bounds__(1024) void k_topk(const float* __restrict__ lg,
                                               float* __restrict__ thr) {
  __shared__ unsigned keys[16384];
  __shared__ unsigned hist[256];
  __shared__ unsigned sh_prefix, sh_krem;
  int b = blockIdx.x, t = threadIdx.x;
  if (t < 256) hist[t] = 0u;
  if (t == 0) { sh_prefix = 0u; sh_krem = 819u; }
  __syncthreads();
  for (int i = t; i < 16384; i += 1024) {
    float vF = lg[(b << 16) + ((i >> 7) << 9) + ((i & 127) << 1)];
    unsigned u = __float_as_uint(vF);
    unsigned key = (u & 0x80000000u) ? ~u : (u | 0x80000000u);
    keys[i] = key;
    atomicAdd(&hist[key >> 24], 1u);
  }
  for (int pass = 0; pass < 4; ++pass) {
    __syncthreads();
    if (t == 0) {
      unsigned krem = sh_krem, c = 0;
      int bin = 255;
      for (; bin >= 0; --bin) {
        unsigned c2 = c + hist[bin];
        if (c2 >= krem) break;
        c = c2;
      }
      sh_prefix = (sh_prefix << 8) | (unsigned)bin;
      sh_krem = krem - c;
    }
    __syncthreads();
    if (pass < 3) {
      if (t < 256) hist[t] = 0u;
      __syncthreads();
      int shift = 16 - 8 * pass;
      unsigned pref = sh_prefix;
      for (int i = t; i < 16384; i += 1024) {
        unsigned key = keys[i];
        if ((key >> (shift + 8)) == pref) atomicAdd(&hist[(key >> shift) & 255u], 1u);
      }
    }
  }
  __syncthreads();
  if (t == 0) {
    unsigned key = sh_prefix;
    unsigned u = (key & 0x80000000u) ? (key ^ 0x80000000u) : ~key;
    thr[b] = __uint_as_float(u);
  }
}

#define FMA8(i, xc)                                                           \
  acc[i][0] = fmaf(xc, wA.x, acc[i][0]); acc[i][1] = fmaf(xc, wA.y, acc[i][1]); \
  acc[i][2] = fmaf(xc, wA.z, acc[i][2]); acc[i][3] = fmaf(xc, wA.w, acc[i][3]); \
  acc[i][4] = fmaf(xc, wB.x, acc[i][4]); acc[i][5] = fmaf(xc, wB.y, acc[i][5]); \
  acc[i][6] = fmaf(xc, wB.z, acc[i][6]); acc[i][7] = fmaf(xc, wB.w, acc[i][7]);

// FUSED dw7x7 + mask + LN + pw1 + gelu. grid (8,8,16), 256 thr.
// y1 layout: [b][chunk=by*8+bx][c 0..31][px 0..255]
__global__ __launch_bounds__(256, 3) void k_dwln(
    const float* __restrict__ feats4x, const float* __restrict__ lg,
    const float* __restrict__ thr, const float* __restrict__ dw_w,
    const float* __restrict__ dw_b, const float* __restrict__ lng,
    const float* __restrict__ lnb, const float* __restrict__ w1,
    const float* __restrict__ b1, float* __restrict__ y1,
    float* __restrict__ gss) {
  int bx = blockIdx.x, by = blockIdx.y, b = blockIdx.z;
  int t = threadIdx.x;
  __shared__ __align__(16) float hx[4][22][24];
  __shared__ __align__(16) float xT[32][256];
  __shared__ __align__(16) float w1T[32][32];
  __shared__ __align__(16) float wdw[32][52];
  __shared__ float sB1[32], sLng[32], sLnb[32];
  for (int i = t; i < 1024; i += 256) w1T[i & 31][i >> 5] = w1[i];
  for (int i = t; i < 1568; i += 256) wdw[i / 49][i % 49] = dw_w[i];
  if (t < 32) { sB1[t] = b1[t]; sLng[t] = lng[t]; sLnb[t] = lnb[t]; }
  int wave = t >> 6, strip = t & 63;
  int py = strip >> 2, px0 = (strip & 3) << 2;

  float4 hr[3];
  auto loadH = [&](int g) {
#pragma unroll
    for (int k = 0; k < 3; ++k) {
      int i = t + (k << 8);
      float4 v = make_float4(0.f, 0.f, 0.f, 0.f);
      if (i < 528) {
        int cl = i / 132, rem = i - cl * 132;
        int hy = rem / 6, hq = rem - hy * 6;
        int gy = (by << 4) + hy - 3;
        int qx = (bx << 4) + (hq << 2) - 4;
        if ((unsigned)gy < 128u && (unsigned)qx < 128u)
          v = *reinterpret_cast<const float4*>(
              feats4x + (((b << 5) + (g << 2) + cl) << 14) + (gy << 7) + qx);
      }
      hr[k] = v;
    }
  };
  auto writeH = [&]() {
#pragma unroll
    for (int k = 0; k < 3; ++k) {
      int i = t + (k << 8);
      if (i < 528) {
        int cl = i / 132, rem = i - cl * 132;
        int hy = rem / 6, hq = rem - hy * 6;
        *reinterpret_cast<float4*>(&hx[cl][hy][hq << 2]) = hr[k];
      }
    }
  };

  loadH(0);
#pragma unroll 1
  for (int g = 0; g < 8; ++g) {
    writeH();
    __syncthreads();
    if (g < 7) loadH(g + 1);
    // compute dw for channel c = g*4 + wave
    {
      int c = (g << 2) + wave;
      float wr[49];
#pragma unroll
      for (int q = 0; q < 12; ++q)
        *reinterpret_cast<float4*>(&wr[q << 2]) =
            *reinterpret_cast<const float4*>(&wdw[c][q << 2]);
      wr[48] = wdw[c][48];
      float bb = dw_b[c];
      float a0 = bb, a1 = bb, a2 = bb, a3 = bb;
#pragma unroll
      for (int ky = 0; ky < 7; ++ky) {
        const float* row = &hx[wave][py + ky][px0];
        float4 r0 = *reinterpret_cast<const float4*>(row);
        float4 r1 = *reinterpret_cast<const float4*>(row + 4);
        float4 r2 = *reinterpret_cast<const float4*>(row + 8);
        float rr[12] = {r0.x, r0.y, r0.z, r0.w, r1.x, r1.y, r1.z, r1.w,
                        r2.x, r2.y, r2.z, r2.w};
#pragma unroll
        for (int kx = 0; kx < 7; ++kx) {
          float wv = wr[ky * 7 + kx];
          a0 = fmaf(rr[kx + 1], wv, a0);
          a1 = fmaf(rr[kx + 2], wv, a1);
          a2 = fmaf(rr[kx + 3], wv, a2);
          a3 = fmaf(rr[kx + 4], wv, a3);
        }
      }
      *reinterpret_cast<float4*>(&xT[c][strip << 2]) = make_float4(a0, a1, a2, a3);
    }
    __syncthreads();
  }
  // ---- per-pixel LN ----
  {
    float tv = thr[b];
    int gpy = (by << 4) + (t >> 4), gpx = (bx << 4) + (t & 15);
    bool act = lg[(b << 16) + (gpy << 9) + (gpx << 1)] > tv;
    float v[32];
    float s = 0.f, s2 = 0.f;
#pragma unroll
    for (int c = 0; c < 32; ++c) {
      float q = xT[c][t];
      v[c] = q;
      s += q;
      s2 += q * q;
    }
    float mu = s * 0.03125f;
    float var = fmaxf(s2 * 0.03125f - mu * mu, 0.f);
    float rs = act ? rsqrtf(var + 1e-6f) : 0.f;
    float mb = act ? 1.f : 0.f;
#pragma unroll
    for (int c = 0; c < 32; ++c)
      xT[c][t] = (v[c] - mu) * rs * sLng[c] + sLnb[c] * mb;
  }
  __syncthreads();
  // ---- pw1 GEMM + gelu + y1c store + gss atomics ----
  int p = t & 63, j0 = wave << 3;
  float acc[4][8];
#pragma unroll
  for (int j = 0; j < 8; ++j) {
    float bj = sB1[j0 + j];
    acc[0][j] = bj; acc[1][j] = bj; acc[2][j] = bj; acc[3][j] = bj;
  }
#pragma unroll
  for (int c = 0; c < 32; ++c) {
    float4 xv = *reinterpret_cast<const float4*>(&xT[c][p << 2]);
    float4 wA = *reinterpret_cast<const float4*>(&w1T[c][j0]);
    float4 wB = *reinterpret_cast<const float4*>(&w1T[c][j0 + 4]);
    FMA8(0, xv.x) FMA8(1, xv.y) FMA8(2, xv.z) FMA8(3, xv.w)
  }
  float part[8] = {0, 0, 0, 0, 0, 0, 0, 0};
#pragma unroll
  for (int i = 0; i < 4; ++i) {
#pragma unroll
    for (int j = 0; j < 8; ++j) {
      float u = acc[i][j];
      float gl = 0.5f * u * (1.f + erf_fast(u * 0.70710678f));
      acc[i][j] = gl;
      part[j] += gl * gl;
    }
  }
  int chunk = (by << 3) + bx;
#pragma unroll
  for (int j = 0; j < 8; ++j) {
    float* yp = y1 + ((((b << 6) + chunk) << 5) + j0 + j) * 256 + (p << 2);
    *reinterpret_cast<float4*>(yp) =
        make_float4(acc[0][j], acc[1][j], acc[2][j], acc[3][j]);
  }
#pragma unroll
  for (int j = 0; j < 8; ++j) {
    float pv = part[j];
#pragma unroll
    for (int off = 1; off < 64; off <<= 1) pv += __shfl_xor(pv, off, 64);
    if (p == 0) atomicAdd(&gss[(b << 5) + j0 + j], pv);
  }
}

__global__ void k_grn(const float* __restrict__ gss, const float* __restrict__ grng,
                      const float* __restrict__ grnb, const float* __restrict__ w2,
                      const float* __restrict__ b2, float* __restrict__ w2sT,
                      float* __restrict__ bias2) {
  int b = blockIdx.x, t = threadIdx.x;
  __shared__ float gxs[32], sc[32];
  if (t < 32) gxs[t] = sqrtf(gss[(b << 5) + t]);
  __syncthreads();
  if (t < 32) {
    float m = 0.f;
#pragma unroll
    for (int c = 0; c < 32; ++c) m += gxs[c];
    m = m * 0.03125f + 1e-6f;
    sc[t] = grng[t] * (gxs[t] / m) + 1.f;
  }
  __syncthreads();
  for (int i = t; i < 1024; i += 256) {
    int c = i >> 5, j = i & 31;
    w2sT[(b << 10) + i] = w2[j * 32 + c] * sc[c];
  }
  if (t < 32) {
    float s = 0.f;
#pragma unroll
    for (int c = 0; c < 32; ++c) s += grnb[c] * w2[t * 32 + c];
    bias2[(b << 5) + t] = s + b2[t];
  }
}

// y1c @ W2s + bias2 + shortcut(feats4x NCHW) -> x_nhwc.
__global__ __launch_bounds__(256, 3) void k_pw2(
    const float* __restrict__ y1c, const float* __restrict__ w2sT,
    const float* __restrict__ bias2, const float* __restrict__ f4,
    float* __restrict__ xo) {
  int b = blockIdx.x >> 6, chunk = blockIdx.x & 63, t = threadIdx.x;
  __shared__ __align__(16) float wT[32][32];
  __shared__ float sb2[32];
  for (int i = t; i < 1024; i += 256) wT[i >> 5][i & 31] = w2sT[(b << 10) + i];
  if (t < 32) sb2[t] = bias2[(b << 5) + t];
  int p = t & 63, j0 = (t >> 6) << 3;
  const float* xp = y1c + (((b << 6) + chunk) << 13) + (p << 2);
  __syncthreads();
  float acc[4][8];
#pragma unroll
  for (int j = 0; j < 8; ++j) {
    float bj = sb2[j0 + j];
    acc[0][j] = bj; acc[1][j] = bj; acc[2][j] = bj; acc[3][j] = bj;
  }
#pragma unroll
  for (int c = 0; c < 32; ++c) {
    float4 xv = *reinterpret_cast<const float4*>(xp + (c << 8));
    float4 wA = *reinterpret_cast<const float4*>(&wT[c][j0]);
    float4 wB = *reinterpret_cast<const float4*>(&wT[c][j0 + 4]);
    FMA8(0, xv.x) FMA8(1, xv.y) FMA8(2, xv.z) FMA8(3, xv.w)
  }
  int ty = chunk >> 3, tx = chunk & 7;
  int y = (ty << 4) + (p >> 2), xb = (tx << 4) + ((p << 2) & 15);
#pragma unroll
  for (int j = 0; j < 8; ++j) {
    float4 sc4 = *reinterpret_cast<const float4*>(
        f4 + (((b << 5) + j0 + j) << 14) + (y << 7) + xb);
    acc[0][j] += sc4.x; acc[1][j] += sc4.y; acc[2][j] += sc4.z; acc[3][j] += sc4.w;
  }
#pragma unroll
  for (int i = 0; i < 4; ++i) {
    float* op = xo + (((b << 14) + (y << 7) + xb + i) << 5) + j0;
    *reinterpret_cast<float4*>(op) = make_float4(acc[i][0], acc[i][1], acc[i][2], acc[i][3]);
    *reinterpret_cast<float4*>(op + 4) = make_float4(acc[i][4], acc[i][5], acc[i][6], acc[i][7]);
  }
}

// 3x3 conv, pad 1, 32x32 tile, 4 px/thread, register-staged single LDS buffer.
// MODE 0: NHWC in (IC=32), +bias+bn        (up branch)
// MODE 1: NCHW in (IC=16), +bias+bn+relu   (shortcut branch)
template <int IC, int OC, int HH, int WW, int MODE>
__global__ __launch_bounds__(256, 3) void k_conv3(
    const float* __restrict__ xin,
    const float* __restrict__ wgt, const float* __restrict__ bias,
    const float* __restrict__ bng, const float* __restrict__ bnb,
    const float* __restrict__ bnm, const float* __restrict__ bnv,
    float* __restrict__ out) {
  constexpr int NG = IC / 4;
  int bx = blockIdx.x << 5, by = blockIdx.y << 5, b = blockIdx.z;
  int t = threadIdx.x;
  int py = t >> 3, px0 = (t & 7) << 2;
  __shared__ __align__(16) float4 xt[34 * 35];
  __shared__ __align__(16) float4 wt[NG * 9 * OC];
  for (int idx = t; idx < NG * 9 * OC; idx += 256) {
    int g = idx / (9 * OC);
    int rem = idx - g * 9 * OC;
    int tap = rem / OC, o = rem - tap * OC;
    int ky = tap / 3, kx = tap - ky * 3;
    float4 wv;
    wv.x = wgt[((o * IC + g * 4 + 0) * 3 + ky) * 3 + kx];
    wv.y = wgt[((o * IC + g * 4 + 1) * 3 + ky) * 3 + kx];
    wv.z = wgt[((o * IC + g * 4 + 2) * 3 + ky) * 3 + kx];
    wv.w = wgt[((o * IC + g * 4 + 3) * 3 + ky) * 3 + kx];
    wt[idx] = wv;
  }
  float acc[4][OC];
#pragma unroll
  for (int i = 0; i < 4; ++i)
#pragma unroll
    for (int o = 0; o < OC; ++o) acc[i][o] = 0.f;

  float4 sr[5];
  auto loadg = [&](int g) {
#pragma unroll
    for (int k = 0; k < 5; ++k) {
      int i = t + (k << 8);
      float4 v = make_float4(0.f, 0.f, 0.f, 0.f);
      if (i < 1156) {
        int r = i / 34, c = i - r * 34;
        int gy = by - 1 + r, gx = bx - 1 + c;
        if ((unsigned)gy < (unsigned)HH && (unsigned)gx < (unsigned)WW) {
          if (MODE == 1) {
            const float* p0 = xin + (((b * IC + (g << 2)) * HH + gy) * WW) + gx;
            v.x = p0[0]; v.y = p0[HH * WW]; v.z = p0[2 * HH * WW]; v.w = p0[3 * HH * WW];
          } else {
            v = *reinterpret_cast<const float4*>(
                xin + (((b * HH) + gy) * WW + gx) * IC + (g << 2));
          }
        }
      }
      sr[k] = v;
    }
  };
  auto writeg = [&]() {
#pragma unroll
    for (int k = 0; k < 5; ++k) {
      int i = t + (k << 8);
      if (i < 1156) {
        int r = i / 34;
        xt[r * 35 + (i - r * 34)] = sr[k];
      }
    }
  };

  loadg(0);
#pragma unroll 1
  for (int g = 0; g < NG; ++g) {
    writeg();
    __syncthreads();
    if (g + 1 < NG) loadg(g + 1);
#pragma unroll
    for (int ky = 0; ky < 3; ++ky) {
      float4 xr[6];
#pragma unroll
      for (int q = 0; q < 6; ++q) xr[q] = xt[(py + ky) * 35 + px0 + q];
#pragma unroll
      for (int kx = 0; kx < 3; ++kx)
#pragma unroll
        for (int o = 0; o < OC; ++o) {
          float4 wv = wt[(g * 9 + ky * 3 + kx) * OC + o];
#pragma unroll
          for (int i = 0; i < 4; ++i) {
            float4 xv = xr[kx + i];
            acc[i][o] = fmaf(xv.w, wv.w, fmaf(xv.z, wv.z, fmaf(xv.y, wv.y, fmaf(xv.x, wv.x, acc[i][o]))));
          }
        }
    }
    __syncthreads();
  }
  float scl[OC], sbs[OC];
#pragma unroll
  for (int o = 0; o < OC; ++o) {
    float rs = rsqrtf(bnv[o] + 1e-5f) * bng[o];
    scl[o] = rs;
    sbs[o] = (bias[o] - bnm[o]) * rs + bnb[o];
  }
  int gy = by + py;
#pragma unroll
  for (int i = 0; i < 4; ++i) {
    int gx = bx + px0 + i;
    float ov[OC];
#pragma unroll
    for (int o = 0; o < OC; ++o) {
      float u = acc[i][o] * scl[o] + sbs[o];
      if (MODE == 1) u = fmaxf(u, 0.f);
      ov[o] = u;
    }
    float* op = out + ((b * HH * WW) + gy * WW + gx) * OC;
    *reinterpret_cast<float4*>(op) = make_float4(ov[0], ov[1], ov[2], ov[3]);
    if (OC == 8)
      *reinterpret_cast<float4*>(op + 4) = make_float4(ov[4], ov[5], ov[6], ov[7]);
  }
}

// last 3x3 conv: on-the-fly bilinear-2x of E (groups 0,1) + D (groups 2,3).
__global__ __launch_bounds__(256, 3) void k_lastup(
    const float* __restrict__ E, const float* __restrict__ D,
    const float* __restrict__ wgt, const float* __restrict__ bias,
    float* __restrict__ out) {
  int bx = blockIdx.x << 5, by = blockIdx.y << 5, b = blockIdx.z;
  int t = threadIdx.x;
  int py = t >> 3, px0 = (t & 7) << 2;
  __shared__ __align__(16) float4 et[19][22][2];
  __shared__ __align__(16) float4 xt[34 * 35];
  __shared__ __align__(16) float4 wt[144];
  for (int idx = t; idx < 144; idx += 256) {
    int g = idx / 36, rem = idx - g * 36;
    int tap = rem >> 2, o = rem & 3;
    int ky = tap / 3, kx = tap - ky * 3;
    float4 wv;
    wv.x = wgt[((o * 16 + g * 4 + 0) * 3 + ky) * 3 + kx];
    wv.y = wgt[((o * 16 + g * 4 + 1) * 3 + ky) * 3 + kx];
    wv.z = wgt[((o * 16 + g * 4 + 2) * 3 + ky) * 3 + kx];
    wv.w = wgt[((o * 16 + g * 4 + 3) * 3 + ky) * 3 + kx];
    wt[idx] = wv;
  }
  float acc[4][4];
#pragma unroll
  for (int i = 0; i < 4; ++i)
#pragma unroll
    for (int o = 0; o < 4; ++o) acc[i][o] = 0.f;

  float4 dreg[5];
  auto loadD = [&](int h) {
#pragma unroll
    for (int k = 0; k < 5; ++k) {
      int i = t + (k << 8);
      float4 v = make_float4(0.f, 0.f, 0.f, 0.f);
      if (i < 1156) {
        int r = i / 34, c = i - r * 34;
        int gy = by - 1 + r, gx = bx - 1 + c;
        if ((unsigned)gy < 256u && (unsigned)gx < 256u)
          v = *reinterpret_cast<const float4*>(
              D + (((b << 16) + (gy << 8) + gx) << 3) + (h << 2));
      }
      dreg[k] = v;
    }
  };
  auto compute = [&](int g) {
#pragma unroll
    for (int ky = 0; ky < 3; ++ky) {
      float4 xr[6];
#pragma unroll
      for (int q = 0; q < 6; ++q) xr[q] = xt[(py + ky) * 35 + px0 + q];
#pragma unroll
      for (int kx = 0; kx < 3; ++kx)
#pragma unroll
        for (int o = 0; o < 4; ++o) {
          float4 wv = wt[(g * 9 + ky * 3 + kx) * 4 + o];
#pragma unroll
          for (int i = 0; i < 4; ++i) {
            float4 xv = xr[kx + i];
            acc[i][o] = fmaf(xv.w, wv.w, fmaf(xv.z, wv.z, fmaf(xv.y, wv.y, fmaf(xv.x, wv.x, acc[i][o]))));
          }
        }
    }
  };

  loadD(0);
  // stage E tile (clamped)
  int ey0 = (by >> 1) - 1, ex0 = (bx >> 1) - 3;
#pragma unroll
  for (int k = 0; k < 4; ++k) {
    int i = t + (k << 8);
    if (i < 836) {
      int h = i & 1, q = i >> 1;
      int r = q / 22, c = q - r * 22;
      int er = min(max(ey0 + r, 0), 127), ec = min(max(ex0 + c, 0), 127);
      et[r][c][h] = *reinterpret_cast<const float4*>(
          E + (((b << 14) + (er << 7) + ec) << 3) + (h << 2));
    }
  }
  // D groups (concat channels 8..15 -> weight groups 2,3)
#pragma unroll 1
  for (int h = 0; h < 2; ++h) {
    __syncthreads();
#pragma unroll
    for (int k = 0; k < 5; ++k) {
      int i = t + (k << 8);
      if (i < 1156) {
        int r = i / 34;
        xt[r * 35 + (i - r * 34)] = dreg[k];
      }
    }
    __syncthreads();
    if (h == 0) loadD(1);
    compute(2 + h);
  }
  // E groups (upsampled on the fly -> weight groups 0,1)
#pragma unroll 1
  for (int h = 0; h < 2; ++h) {
    __syncthreads();
#pragma unroll
    for (int k = 0; k < 5; ++k) {
      int i = t + (k << 8);
      if (i < 1156) {
        int r = i / 34, c = i - r * 34;
        int gy = by - 1 + r, gx = bx - 1 + c;
        float4 uv = make_float4(0.f, 0.f, 0.f, 0.f);
        if ((unsigned)gy < 256u && (unsigned)gx < 256u) {
          int r0 = (gy - 1) >> 1, c0 = (gx - 1) >> 1;
          float fy = (gy & 1) ? 0.25f : 0.75f;
          float fx = (gx & 1) ? 0.25f : 0.75f;
          int ra = max(r0, 0) - ey0, rb = min(r0 + 1, 127) - ey0;
          int ca = max(c0, 0) - ex0, cb = min(c0 + 1, 127) - ex0;
          float w00 = (1.f - fy) * (1.f - fx), w01 = (1.f - fy) * fx;
          float w10 = fy * (1.f - fx), w11 = fy * fx;
          float4 a = et[ra][ca][h], bq = et[ra][cb][h];
          float4 cq = et[rb][ca][h], dq = et[rb][cb][h];
          uv.x = w00 * a.x + w01 * bq.x + w10 * cq.x + w11 * dq.x;
          uv.y = w00 * a.y + w01 * bq.y + w10 * cq.y + w11 * dq.y;
          uv.z = w00 * a.z + w01 * bq.z + w10 * cq.z + w11 * dq.z;
          uv.w = w00 * a.w + w01 * bq.w + w10 * cq.w + w11 * dq.w;
        }
        xt[r * 35 + c] = uv;
      }
    }
    __syncthreads();
    compute(h);
  }
  float b0 = bias[0], b1v = bias[1], b2v = bias[2], b3v = bias[3];
  int gy = by + py;
#pragma unroll
  for (int i = 0; i < 4; ++i) {
    int gx = bx + px0 + i;
    float* op = out + (((b << 16) + (gy << 8) + gx) << 2);
    *reinterpret_cast<float4*>(op) = make_float4(acc[i][0] + b0, acc[i][1] + b1v,
                                                 acc[i][2] + b2v, acc[i][3] + b3v);
  }
}

// bilinear 2x (256->512, zero outside) + 5x5 conv pad 2 + sigmoid -> out1
__global__ __launch_bounds__(256, 3) void k_final(
    const float* __restrict__ v4, const float* __restrict__ w5,
    const float* __restrict__ b5, float* __restrict__ out) {
  int bx = blockIdx.x << 5, by = blockIdx.y << 5, b = blockIdx.z;
  int t = threadIdx.x;
  __shared__ __align__(16) float4 vt[20 * 20];
  __shared__ __align__(16) float4 ut[36 * 38];
  __shared__ __align__(16) float4 w5s[25];
  if (t < 25) {
    w5s[t] = make_float4(w5[t], w5[25 + t], w5[50 + t], w5[75 + t]);
  }
  int vy0 = (by >> 1) - 2, vx0 = (bx >> 1) - 2;
  for (int i = t; i < 400; i += 256) {
    int r = i / 20, c = i - r * 20;
    int gy = vy0 + r, gx = vx0 + c;
    float4 v = make_float4(0.f, 0.f, 0.f, 0.f);
    if (gy >= 0 && gy < 256 && gx >= 0 && gx < 256)
      v = *reinterpret_cast<const float4*>(v4 + ((b << 16) + gy * 256 + gx) * 4);
    vt[i] = v;
  }
  __syncthreads();
  for (int i = t; i < 36 * 36; i += 256) {
    int r = i / 36, c = i - r * 36;
    int yy = by - 2 + r, xx = bx - 2 + c;
    float4 uv = make_float4(0.f, 0.f, 0.f, 0.f);
    if (yy >= 0 && yy < 512 && xx >= 0 && xx < 512) {
      int r0 = (yy - 1) >> 1, c0 = (xx - 1) >> 1;
      float fy = (yy & 1) ? 0.25f : 0.75f;
      float fx = (xx & 1) ? 0.25f : 0.75f;
      int ra = max(r0, 0) - vy0, rb = min(r0 + 1, 255) - vy0;
      int ca = max(c0, 0) - vx0, cb = min(c0 + 1, 255) - vx0;
      float4 a = vt[ra * 20 + ca], bq = vt[ra * 20 + cb];
      float4 cq = vt[rb * 20 + ca], dq = vt[rb * 20 + cb];
      float w00 = (1.f - fy) * (1.f - fx), w01 = (1.f - fy) * fx;
      float w10 = fy * (1.f - fx), w11 = fy * fx;
      uv.x = w00 * a.x + w01 * bq.x + w10 * cq.x + w11 * dq.x;
      uv.y = w00 * a.y + w01 * bq.y + w10 * cq.y + w11 * dq.y;
      uv.z = w00 * a.z + w01 * bq.z + w10 * cq.z + w11 * dq.z;
      uv.w = w00 * a.w + w01 * bq.w + w10 * cq.w + w11 * dq.w;
    }
    ut[r * 38 + c] = uv;
  }
  __syncthreads();
  float bb = b5[0];
  int py = (t >> 4) << 1, px = (t & 15) << 1;
  float acc00 = bb, acc01 = bb, acc10 = bb, acc11 = bb;
#pragma unroll
  for (int ri = 0; ri < 6; ++ri) {
    float4 xr[6];
#pragma unroll
    for (int q = 0; q < 6; ++q) xr[q] = ut[(py + ri) * 38 + px + q];
#pragma unroll
    for (int i = 0; i < 2; ++i) {
      int ky = ri - i;
      if (ky >= 0 && ky < 5) {
#pragma unroll
        for (int kx = 0; kx < 5; ++kx) {
          float4 w = w5s[ky * 5 + kx];
          float4 xa = xr[kx], xb = xr[kx + 1];
          if (i == 0) {
            acc00 = fmaf(xa.w, w.w, fmaf(xa.z, w.z, fmaf(xa.y, w.y, fmaf(xa.x, w.x, acc00))));
            acc01 = fmaf(xb.w, w.w, fmaf(xb.z, w.z, fmaf(xb.y, w.y, fmaf(xb.x, w.x, acc01))));
          } else {
            acc10 = fmaf(xa.w, w.w, fmaf(xa.z, w.z, fmaf(xa.y, w.y, fmaf(xa.x, w.x, acc10))));
            acc11 = fmaf(xb.w, w.w, fmaf(xb.z, w.z, fmaf(xb.y, w.y, fmaf(xb.x, w.x, acc11))));
          }
        }
      }
    }
  }
  int oy = by + py, ox = bx + px;
  float* op = out + (b << 18) + oy * 512 + ox;
  *reinterpret_cast<float2*>(op) =
      make_float2(1.f / (1.f + __expf(-acc00)), 1.f / (1.f + __expf(-acc01)));
  *reinterpret_cast<float2*>(op + 512) =
      make_float2(1.f / (1.f + __expf(-acc10)), 1.f / (1.f + __expf(-acc11)));
}

extern "C" void kernel_launch(void* const* d_in, const int* in_sizes, int n_in,
                              void* d_out, int out_size, void* d_ws, size_t ws_size,
                              hipStream_t stream) {
  (void)in_sizes; (void)n_in; (void)out_size; (void)ws_size;
  const float* feats4x = (const float*)d_in[0];
  const float* feats2x = (const float*)d_in[1];
  const float* clg     = (const float*)d_in[2];
  const float* dw_w    = (const float*)d_in[3];
  const float* dw_b    = (const float*)d_in[4];
  const float* ln_g    = (const float*)d_in[5];
  const float* ln_b    = (const float*)d_in[6];
  const float* pw1_w   = (const float*)d_in[7];
  const float* pw1_b   = (const float*)d_in[8];
  const float* grn_g   = (const float*)d_in[9];
  const float* grn_b   = (const float*)d_in[10];
  const float* pw2_w   = (const float*)d_in[11];
  const float* pw2_b   = (const float*)d_in[12];
  const float* up_w    = (const float*)d_in[13];
  const float* up_b    = (const float*)d_in[14];
  const float* bn1_g   = (const float*)d_in[15];
  const float* bn1_b   = (const float*)d_in[16];
  const float* bn1_m   = (const float*)d_in[17];
  const float* bn1_v   = (const float*)d_in[18];
  const float* sh_w    = (const float*)d_in[19];
  const float* sh_b    = (const float*)d_in[20];
  const float* bn2_g   = (const float*)d_in[21];
  const float* bn2_b   = (const float*)d_in[22];
  const float* bn2_m   = (const float*)d_in[23];
  const float* bn2_v   = (const float*)d_in[24];
  const float* last_w  = (const float*)d_in[25];
  const float* last_b  = (const float*)d_in[26];
  const float* last2_w = (const float*)d_in[27];
  const float* last2_b = (const float*)d_in[28];
  float* outp = (float*)d_out;
  float* ws = (float*)d_ws;
  float* A    = ws;              // x_nhwc -> lastup out (v4)
  float* Bb   = ws + 8388608;    // y1c
  float* D    = ws + 16777216;   // s8 (shortcut branch, NHWC8 256^2)
  float* E    = ws + 25165824;   // up-conv out (NHWC8 128^2)
  float* thr  = ws + 27262976;
  float* gss  = thr + 16;
  float* w2sT = gss + 512;
  float* bias2 = w2sT + 16384;

  hipMemsetAsync(gss, 0, 512 * sizeof(float), stream);
  k_sig<<<1024, 256, 0, stream>>>(clg, outp + 4194304);
  k_topk<<<16, 1024, 0, stream>>>(clg, thr);
  k_dwln<<<dim3(8, 8, 16), 256, 0, stream>>>(feats4x, clg, thr, dw_w, dw_b,
                                             ln_g, ln_b, pw1_w, pw1_b, Bb, gss);
  k_grn<<<16, 256, 0, stream>>>(gss, grn_g, grn_b, pw2_w, pw2_b, w2sT, bias2);
  k_pw2<<<1024, 256, 0, stream>>>(Bb, w2sT, bias2, feats4x, A);
  k_conv3<32, 8, 128, 128, 0><<<dim3(4, 4, 16), 256, 0, stream>>>(
      A, up_w, up_b, bn1_g, bn1_b, bn1_m, bn1_v, E);
  k_conv3<16, 8, 256, 256, 1><<<dim3(8, 8, 16), 256, 0, stream>>>(
      feats2x, sh_w, sh_b, bn2_g, bn2_b, bn2_m, bn2_v, D);
  k_lastup<<<dim3(8, 8, 16), 256, 0, stream>>>(E, D, last_w, last_b, A);
  k_final<<<dim3(16, 16, 16), 256, 0, stream>>>(A, last2_w, last2_b, outp);
}